// Round 7
// baseline (153.962 us; speedup 1.0000x reference)
//
#include <hip/hip_runtime.h>
#include <hip/hip_fp16.h>
#include <math.h>

#define SLOPE 0.01f
#define NLAYER 15
#define FINE_CELLS 512            // [-2, 2), h = 1/128
#define COARSE_CELLS 128          // [-32, 32), h = 1/2; extrapolate via clamped end cells
#define CELLS 640                 // per layer; cell = uint2: half2(s_m,s_v), half2(t_m,t_v)
#define FINE_NODES 513
#define NODES_PER_NET 642
#define TABLE_CELLS (NLAYER * CELLS)     // 9600 uint2 = 76800 B -> 2 blocks/CU
#define INV_LN2 1.4426950408889634f
#define LN2F 0.6931471805599453f

__device__ __forceinline__ float fast_exp2(float x) {
#if __has_builtin(__builtin_amdgcn_exp2f)
    return __builtin_amdgcn_exp2f(x);
#else
    return __expf(x * LN2F);
#endif
}

// ---------------- exact scalar->32->16->1 MLP (precompute only) ----------------
__device__ __forceinline__ float mlp_exact(
    float x1,
    const float* __restrict__ W1, const float* __restrict__ b1,
    const float* __restrict__ W2, const float* __restrict__ b2,
    const float* __restrict__ W3, float b3)
{
    float h2[16];
#pragma unroll
    for (int n = 0; n < 16; ++n) h2[n] = b2[n];
#pragma unroll 2
    for (int j = 0; j < 32; ++j) {
        float h = fmaf(W1[j], x1, b1[j]);
        h = fmaxf(h, SLOPE * h);
#pragma unroll
        for (int n = 0; n < 16; ++n) h2[n] = fmaf(h, W2[j * 16 + n], h2[n]);
    }
    float o = b3;
#pragma unroll
    for (int n = 0; n < 16; ++n) {
        float h = fmaxf(h2[n], SLOPE * h2[n]);
        o = fmaf(h, W3[n], o);
    }
    return o;
}

// ---------------- build: one block per net (30 blocks) ----
// Cell stores CENTER-REFERENCED f16 slope/value: val(x) = m*(x - x_center) + v.
// |dx| <= h/2, so f16 error hits v (rel 2^-11) and m*dx (tiny) — much better
// than an f16 intercept at x=0. s-net values are in log2 units.
__global__ __launch_bounds__(640) void build_tables(
    const float* __restrict__ scale_w, const float* __restrict__ scale_b,
    const float* __restrict__ sW1, const float* __restrict__ sb1,
    const float* __restrict__ sW2, const float* __restrict__ sb2,
    const float* __restrict__ sW3, const float* __restrict__ sb3,
    const float* __restrict__ tW1, const float* __restrict__ tb1,
    const float* __restrict__ tW2, const float* __restrict__ tb2,
    const float* __restrict__ tW3, const float* __restrict__ tb3,
    float* __restrict__ ws)
{
    const int m = blockIdx.x;            // 0..29
    const int l = m >> 1;
    const int which = m & 1;             // 0 = s-net, 1 = t-net
    const float* W1 = (which ? tW1 : sW1) + l * 32;
    const float* b1 = (which ? tb1 : sb1) + l * 32;
    const float* W2 = (which ? tW2 : sW2) + l * 512;
    const float* b2 = (which ? tb2 : sb2) + l * 16;
    const float* W3 = (which ? tW3 : sW3) + l * 16;
    const float  b3 = which ? tb3[l] : sb3[l];

    __shared__ float nodes[NODES_PER_NET];

    for (int i = threadIdx.x; i < NODES_PER_NET; i += blockDim.x) {
        const float x = (i < FINE_NODES) ? (-2.0f + (float)i * (1.0f / 128.0f))
                                         : (-32.0f + (float)(i - FINE_NODES) * 0.5f);
        float o = mlp_exact(x, W1, b1, W2, b2, W3, b3);
        nodes[i] = which ? o : fmaf(tanhf(o), scale_w[l], scale_b[l]) * INV_LN2;
    }
    __syncthreads();

    for (int c = threadIdx.x; c < CELLS; c += blockDim.x) {
        int base; float invh;
        if (c < FINE_CELLS) { base = c;     invh = 128.0f; }
        else                { base = c + 1; invh = 2.0f; }
        float lo = nodes[base], hi = nodes[base + 1];
        float slope = (hi - lo) * invh;
        float vmid  = 0.5f * (lo + hi);                 // value at cell center
        __half2 h2 = __floats2half2_rn(slope, vmid);    // low = m, high = v
        ((__half2*)ws)[(size_t)(l * CELLS + c) * 2 + which] = h2;
    }
}

// ---------------- index + center-offset ----------------
// Fine: u = 128x+256 in [0,512), trunc == floor. Coarse: clamp index to
// [512,639]; dx uses the UNCLAMPED u so end cells extrapolate linearly.
__device__ __forceinline__ void cell_addr(float x, int* idx, float* dx) {
    float uf = fmaf(x, 128.0f, 256.0f);
    float uc = fmaf(x, 2.0f, 576.0f);
    bool fine = (fabsf(x) < 2.0f);
    float ucl = fminf(fmaxf(uc, 512.0f), 639.0f);
    float fi = fine ? uf : ucl;          // for index
    int i = (int)fi;                     // trunc
    float fu = (float)i;
    float u = fine ? uf : uc;            // unclamped for dx
    float h = fine ? 0.0078125f : 0.5f;
    *idx = i;
    *dx = (u - fu - 0.5f) * h;           // x - cell_center
}

// ---------------- main flow: whole f16 table in LDS, 2 blocks/CU --------------
// 512 blocks x 1024 threads; LDS 76800 B -> 2 blocks/CU (32 waves) iff VGPR<=64
// (__launch_bounds__(1024,2): under CUDA blocks-per-CU semantics targets 64
// VGPR; under waves-per-EU semantics it's a harmless 256 cap — R3 postmortem).
// One ds_read_b64 per eval: 16 bank-groups (vs 8 for b128) halves conflicts.
// 4 independent chains per thread iteration for gather ILP (R6 win, kept).
__global__ __launch_bounds__(1024, 2) void flow_lut(
    const float4* __restrict__ x,      // pairs of float2 samples
    const float4* __restrict__ ws,     // staged f16 cell table
    float4* __restrict__ out_z,
    float2* __restrict__ out_ld,
    int npair)
{
    __shared__ __align__(16) uint2 lds[TABLE_CELLS];   // 76800 B
    {
        float4* dst = (float4*)lds;
        for (int i = threadIdx.x; i < TABLE_CELLS / 2; i += blockDim.x) dst[i] = ws[i];
    }
    __syncthreads();

    const int tid = blockIdx.x * blockDim.x + threadIdx.x;
    const int stride = gridDim.x * blockDim.x;

    for (int p0 = tid; p0 < npair; p0 += 2 * stride) {
        const int p1 = p0 + stride;
        const bool has1 = (p1 < npair);
        float4 xa = x[p0];
        float4 xb = has1 ? x[p1] : make_float4(0.f, 0.f, 0.f, 0.f);

        float az1 = xa.y, az2 = xa.x, ald = 0.f;
        float bz1 = xa.w, bz2 = xa.z, bld = 0.f;
        float cz1 = xb.y, cz2 = xb.x, cld = 0.f;
        float dz1 = xb.w, dz2 = xb.z, dld = 0.f;

#pragma unroll
        for (int l = 0; l < NLAYER; ++l) {
            const uint2* T = lds + l * CELLS;
            int ia, ib, ic, id;
            float dxa, dxb, dxc, dxd;
            cell_addr(az2, &ia, &dxa);
            cell_addr(bz2, &ib, &dxb);
            cell_addr(cz2, &ic, &dxc);
            cell_addr(dz2, &id, &dxd);
            // 4 independent b64 gathers in flight before any dependent VALU
            uint2 ca = T[ia];
            uint2 cb = T[ib];
            uint2 cc = T[ic];
            uint2 cd = T[id];

            __half2 ash = *(const __half2*)&ca.x, ath = *(const __half2*)&ca.y;
            __half2 bsh = *(const __half2*)&cb.x, bth = *(const __half2*)&cb.y;
            __half2 csh = *(const __half2*)&cc.x, cth = *(const __half2*)&cc.y;
            __half2 dsh = *(const __half2*)&cd.x, dth = *(const __half2*)&cd.y;

            float als = fmaf(__low2float(ash), dxa, __high2float(ash));
            float ag  = fmaf(__low2float(ath), dxa, __high2float(ath));
            float bls = fmaf(__low2float(bsh), dxb, __high2float(bsh));
            float bg  = fmaf(__low2float(bth), dxb, __high2float(bth));
            float cls = fmaf(__low2float(csh), dxc, __high2float(csh));
            float cg  = fmaf(__low2float(cth), dxc, __high2float(cth));
            float dls = fmaf(__low2float(dsh), dxd, __high2float(dsh));
            float dg  = fmaf(__low2float(dth), dxd, __high2float(dth));

            float az2n = fmaf(fast_exp2(als), az1, ag);
            float bz2n = fmaf(fast_exp2(bls), bz1, bg);
            float cz2n = fmaf(fast_exp2(cls), cz1, cg);
            float dz2n = fmaf(fast_exp2(dls), dz1, dg);

            az1 = az2; az2 = az2n; ald += als;
            bz1 = bz2; bz2 = bz2n; bld += bls;
            cz1 = cz2; cz2 = cz2n; cld += cls;
            dz1 = dz2; dz2 = dz2n; dld += dls;
        }

        out_z[p0]  = make_float4(az1, az2, bz1, bz2);
        out_ld[p0] = make_float2(ald * LN2F, bld * LN2F);
        if (has1) {
            out_z[p1]  = make_float4(cz1, cz2, dz1, dz2);
            out_ld[p1] = make_float2(cld * LN2F, dld * LN2F);
        }
    }
}

extern "C" void kernel_launch(void* const* d_in, const int* in_sizes, int n_in,
                              void* d_out, int out_size, void* d_ws, size_t ws_size,
                              hipStream_t stream) {
    const int n = in_sizes[0] / 2;
    const int npair = n / 2;             // N = 4194304 is even

    const float4* x       = (const float4*)d_in[0];
    const float*  scale_w = (const float*)d_in[1];
    const float*  scale_b = (const float*)d_in[2];
    const float*  sW1     = (const float*)d_in[3];
    const float*  sb1     = (const float*)d_in[4];
    const float*  sW2     = (const float*)d_in[5];
    const float*  sb2     = (const float*)d_in[6];
    const float*  sW3     = (const float*)d_in[7];
    const float*  sb3     = (const float*)d_in[8];
    const float*  tW1     = (const float*)d_in[9];
    const float*  tb1     = (const float*)d_in[10];
    const float*  tW2     = (const float*)d_in[11];
    const float*  tb2     = (const float*)d_in[12];
    const float*  tW3     = (const float*)d_in[13];
    const float*  tb3     = (const float*)d_in[14];

    float4* out_z  = (float4*)d_out;
    float2* out_ld = (float2*)((float*)d_out + (size_t)2 * n);

    build_tables<<<30, 640, 0, stream>>>(scale_w, scale_b,
        sW1, sb1, sW2, sb2, sW3, sb3,
        tW1, tb1, tW2, tb2, tW3, tb3, (float*)d_ws);

    flow_lut<<<512, 1024, 0, stream>>>(x, (const float4*)d_ws, out_z, out_ld, npair);
}

// Round 8
// 152.029 us; speedup vs baseline: 1.0127x; 1.0127x over previous
//
#include <hip/hip_runtime.h>
#include <hip/hip_fp16.h>
#include <math.h>

#define SLOPE 0.01f
#define NLAYER 15
#define FINE_CELLS 512            // [-2, 2), h = 1/128
#define COARSE_CELLS 128          // [-32, 32), h = 1/2; extrapolate via clamped end cells
#define CELLS 640                 // per layer; cell = uint2: half2(s_m,s_v), half2(t_m,t_v)
#define FINE_NODES 513
#define NODES_PER_NET 642
#define TABLE_CELLS (NLAYER * CELLS)     // 9600 uint2 = 76800 B
#define INV_LN2 1.4426950408889634f
#define LN2F 0.6931471805599453f

__device__ __forceinline__ float fast_exp2(float x) {
#if __has_builtin(__builtin_amdgcn_exp2f)
    return __builtin_amdgcn_exp2f(x);
#else
    return __expf(x * LN2F);
#endif
}

// ---------------- exact scalar->32->16->1 MLP (precompute only) ----------------
__device__ __forceinline__ float mlp_exact(
    float x1,
    const float* __restrict__ W1, const float* __restrict__ b1,
    const float* __restrict__ W2, const float* __restrict__ b2,
    const float* __restrict__ W3, float b3)
{
    float h2[16];
#pragma unroll
    for (int n = 0; n < 16; ++n) h2[n] = b2[n];
#pragma unroll 2
    for (int j = 0; j < 32; ++j) {
        float h = fmaf(W1[j], x1, b1[j]);
        h = fmaxf(h, SLOPE * h);
#pragma unroll
        for (int n = 0; n < 16; ++n) h2[n] = fmaf(h, W2[j * 16 + n], h2[n]);
    }
    float o = b3;
#pragma unroll
    for (int n = 0; n < 16; ++n) {
        float h = fmaxf(h2[n], SLOPE * h2[n]);
        o = fmaf(h, W3[n], o);
    }
    return o;
}

// ---------------- build: one block per net (30 blocks) ----
// Cell stores CENTER-REFERENCED f16 (slope-per-index-step, center value):
//   val(u) = m*(u - i - 0.5) + v,  u = index-space coordinate, m = hi - lo.
// |du| <= 0.5 so f16 error hits v (rel 2^-11) and m*du (tiny).
// s-net values are in log2 units. (Format accuracy verified R7: absmax 0.125.)
__global__ __launch_bounds__(640) void build_tables(
    const float* __restrict__ scale_w, const float* __restrict__ scale_b,
    const float* __restrict__ sW1, const float* __restrict__ sb1,
    const float* __restrict__ sW2, const float* __restrict__ sb2,
    const float* __restrict__ sW3, const float* __restrict__ sb3,
    const float* __restrict__ tW1, const float* __restrict__ tb1,
    const float* __restrict__ tW2, const float* __restrict__ tb2,
    const float* __restrict__ tW3, const float* __restrict__ tb3,
    float* __restrict__ ws)
{
    const int m = blockIdx.x;            // 0..29
    const int l = m >> 1;
    const int which = m & 1;             // 0 = s-net, 1 = t-net
    const float* W1 = (which ? tW1 : sW1) + l * 32;
    const float* b1 = (which ? tb1 : sb1) + l * 32;
    const float* W2 = (which ? tW2 : sW2) + l * 512;
    const float* b2 = (which ? tb2 : sb2) + l * 16;
    const float* W3 = (which ? tW3 : sW3) + l * 16;
    const float  b3 = which ? tb3[l] : sb3[l];

    __shared__ float nodes[NODES_PER_NET];

    for (int i = threadIdx.x; i < NODES_PER_NET; i += blockDim.x) {
        const float x = (i < FINE_NODES) ? (-2.0f + (float)i * (1.0f / 128.0f))
                                         : (-32.0f + (float)(i - FINE_NODES) * 0.5f);
        float o = mlp_exact(x, W1, b1, W2, b2, W3, b3);
        nodes[i] = which ? o : fmaf(tanhf(o), scale_w[l], scale_b[l]) * INV_LN2;
    }
    __syncthreads();

    for (int c = threadIdx.x; c < CELLS; c += blockDim.x) {
        const int base = (c < FINE_CELLS) ? c : (c + 1);
        float lo = nodes[base], hi = nodes[base + 1];
        float slope = hi - lo;                          // per index step
        float vmid  = 0.5f * (lo + hi);                 // value at cell center
        __half2 h2 = __floats2half2_rn(slope, vmid);    // low = m, high = v
        ((__half2*)ws)[(size_t)(l * CELLS + c) * 2 + which] = h2;
    }
}

// ---------------- index + center-offset (index units) ----------------
// Fine: u = 128x+256 in [0,512), trunc == floor. Coarse: clamp index to
// [512,639]; du uses the UNCLAMPED u so end cells extrapolate linearly.
__device__ __forceinline__ void cell_addr(float x, int* idx, float* du) {
    float uf = fmaf(x, 128.0f, 256.0f);
    float uc = fmaf(x, 2.0f, 576.0f);
    bool fine = (fabsf(x) < 2.0f);
    float ucl = fminf(fmaxf(uc, 512.0f), 639.0f);   // v_med3_f32
    float fi = fine ? uf : ucl;          // for index
    int i = (int)fi;                     // trunc == floor (u >= 0)
    float u = fine ? uf : uc;            // unclamped for du
    *idx = i;
    *du = u - (float)i - 0.5f;           // index-space offset from cell center
}

// ---------------- main flow: whole f16 table in LDS (R6 structure) ------------
// 256 blocks x 1024 threads, 1 block/CU, zero barriers in the main loop.
// Plain __launch_bounds__(1024) — NEVER pass a min-waves 2nd arg: (512,8) and
// (1024,2) both produced a 32-VGPR clamp (R3 spill disaster, R7 ILP collapse).
// One ds_read_b64 per eval (16 bank-groups: conflicts 7.52M -> 4.33M, R7-
// verified); 4 independent chains per thread iteration for gather ILP (R6 win).
__global__ __launch_bounds__(1024) void flow_lut(
    const float4* __restrict__ x,      // pairs of float2 samples
    const float4* __restrict__ ws,     // staged f16 cell table
    float4* __restrict__ out_z,
    float2* __restrict__ out_ld,
    int npair)
{
    __shared__ __align__(16) uint2 lds[TABLE_CELLS];   // 76800 B
    {
        float4* dst = (float4*)lds;
        for (int i = threadIdx.x; i < TABLE_CELLS / 2; i += blockDim.x) dst[i] = ws[i];
    }
    __syncthreads();

    const int tid = blockIdx.x * blockDim.x + threadIdx.x;
    const int stride = gridDim.x * blockDim.x;

    for (int p0 = tid; p0 < npair; p0 += 2 * stride) {
        const int p1 = p0 + stride;
        const bool has1 = (p1 < npair);
        float4 xa = x[p0];
        float4 xb = has1 ? x[p1] : make_float4(0.f, 0.f, 0.f, 0.f);

        float az1 = xa.y, az2 = xa.x, ald = 0.f;
        float bz1 = xa.w, bz2 = xa.z, bld = 0.f;
        float cz1 = xb.y, cz2 = xb.x, cld = 0.f;
        float dz1 = xb.w, dz2 = xb.z, dld = 0.f;

#pragma unroll
        for (int l = 0; l < NLAYER; ++l) {
            const uint2* T = lds + l * CELLS;
            int ia, ib, ic, id;
            float dua, dub, duc, dud;
            cell_addr(az2, &ia, &dua);
            cell_addr(bz2, &ib, &dub);
            cell_addr(cz2, &ic, &duc);
            cell_addr(dz2, &id, &dud);
            // 4 independent b64 gathers in flight before any dependent VALU
            uint2 ca = T[ia];
            uint2 cb = T[ib];
            uint2 cc = T[ic];
            uint2 cd = T[id];

            __half2 ash = *(const __half2*)&ca.x, ath = *(const __half2*)&ca.y;
            __half2 bsh = *(const __half2*)&cb.x, bth = *(const __half2*)&cb.y;
            __half2 csh = *(const __half2*)&cc.x, cth = *(const __half2*)&cc.y;
            __half2 dsh = *(const __half2*)&cd.x, dth = *(const __half2*)&cd.y;

            float als = fmaf(__low2float(ash), dua, __high2float(ash));
            float ag  = fmaf(__low2float(ath), dua, __high2float(ath));
            float bls = fmaf(__low2float(bsh), dub, __high2float(bsh));
            float bg  = fmaf(__low2float(bth), dub, __high2float(bth));
            float cls = fmaf(__low2float(csh), duc, __high2float(csh));
            float cg  = fmaf(__low2float(cth), duc, __high2float(cth));
            float dls = fmaf(__low2float(dsh), dud, __high2float(dsh));
            float dg  = fmaf(__low2float(dth), dud, __high2float(dth));

            float az2n = fmaf(fast_exp2(als), az1, ag);
            float bz2n = fmaf(fast_exp2(bls), bz1, bg);
            float cz2n = fmaf(fast_exp2(cls), cz1, cg);
            float dz2n = fmaf(fast_exp2(dls), dz1, dg);

            az1 = az2; az2 = az2n; ald += als;
            bz1 = bz2; bz2 = bz2n; bld += bls;
            cz1 = cz2; cz2 = cz2n; cld += cls;
            dz1 = dz2; dz2 = dz2n; dld += dls;
        }

        out_z[p0]  = make_float4(az1, az2, bz1, bz2);
        out_ld[p0] = make_float2(ald * LN2F, bld * LN2F);
        if (has1) {
            out_z[p1]  = make_float4(cz1, cz2, dz1, dz2);
            out_ld[p1] = make_float2(cld * LN2F, dld * LN2F);
        }
    }
}

extern "C" void kernel_launch(void* const* d_in, const int* in_sizes, int n_in,
                              void* d_out, int out_size, void* d_ws, size_t ws_size,
                              hipStream_t stream) {
    const int n = in_sizes[0] / 2;
    const int npair = n / 2;             // N = 4194304 is even

    const float4* x       = (const float4*)d_in[0];
    const float*  scale_w = (const float*)d_in[1];
    const float*  scale_b = (const float*)d_in[2];
    const float*  sW1     = (const float*)d_in[3];
    const float*  sb1     = (const float*)d_in[4];
    const float*  sW2     = (const float*)d_in[5];
    const float*  sb2     = (const float*)d_in[6];
    const float*  sW3     = (const float*)d_in[7];
    const float*  sb3     = (const float*)d_in[8];
    const float*  tW1     = (const float*)d_in[9];
    const float*  tb1     = (const float*)d_in[10];
    const float*  tW2     = (const float*)d_in[11];
    const float*  tb2     = (const float*)d_in[12];
    const float*  tW3     = (const float*)d_in[13];
    const float*  tb3     = (const float*)d_in[14];

    float4* out_z  = (float4*)d_out;
    float2* out_ld = (float2*)((float*)d_out + (size_t)2 * n);

    build_tables<<<30, 640, 0, stream>>>(scale_w, scale_b,
        sW1, sb1, sW2, sb2, sW3, sb3,
        tW1, tb1, tW2, tb2, tW3, tb3, (float*)d_ws);

    flow_lut<<<256, 1024, 0, stream>>>(x, (const float4*)d_ws, out_z, out_ld, npair);
}